// Round 2
// baseline (243.387 us; speedup 1.0000x reference)
//
#include <hip/hip_runtime.h>

namespace {

constexpr int Bn      = 64;
constexpr int QN      = 16;
constexpr int Dn      = 64;
constexpr int DVn     = 64;
constexpr int KVn     = 16384;
constexpr int MAX_SPLITS = 32;
constexpr int TILE    = 64;             // keys per tile
constexpr int THREADS = 256;

// LDS row pitches (floats). KP/AP = 68 floats = 272 B = 17*16B: odd multiple of
// 16B -> b128 row-per-lane reads spread across all 8 bank quads. SP = 20 floats
// (16 values + 4 pad). VP = 64: column reads are lane==bank (2-way, free).
constexpr int KP = 68;   // K tile row pitch (row holds 64 floats)  -> 17 KB
constexpr int SP = 20;   // S tile row pitch (row holds 16 floats)  ->  5 KB
constexpr int QP = 64;   // Q row pitch (broadcast reads)           ->  4 KB
constexpr int AP = 68;   // A row pitch (row holds 64 floats)       -> 4.25 KB
constexpr int VP = 64;   // V row pitch                             -> 16 KB

constexpr float SCALE = 0.125f * 1.4426950408889634f;  // (1/sqrt(64)) * log2(e)

__device__ __forceinline__ float dot4(float4 a, float4 b, float acc) {
    return fmaf(a.x, b.x, fmaf(a.y, b.y, fmaf(a.z, b.z, fmaf(a.w, b.w, acc))));
}

__global__ __launch_bounds__(THREADS, 3)
void inv_attn_part(const float* __restrict__ query,
                   const float* __restrict__ key,
                   const float* __restrict__ value,
                   float* __restrict__ pout,   // [B][splits][QN][DVn]
                   float* __restrict__ pden,   // [B][splits][QN]
                   int ntiles)
{
    __shared__ __align__(16) float q_lds[QN * QP];
    __shared__ __align__(16) float k_lds[TILE * KP];
    __shared__ __align__(16) float s_lds[TILE * SP];
    __shared__ __align__(16) float a_lds[QN * AP];
    __shared__ __align__(16) float v_lds[TILE * VP];

    const int tid  = threadIdx.x;
    const int lane = tid & 63;
    const int w    = tid >> 6;      // wave id 0..3; wave owns q = 4w..4w+3
    const int spl  = blockIdx.x;
    const int splits = gridDim.x;
    const int b    = blockIdx.y;
    const int key_base = spl * ntiles * TILE;
    const int q0 = 4 * w;

    // ---- stage Q, pre-scaled so QK^T lands in log2 domain ----
    {
        const int qr = tid >> 4, c = tid & 15;   // 16 rows x 16 chunks
        float4 v = *reinterpret_cast<const float4*>(
            query + ((size_t)b * QN + qr) * Dn + c * 4);
        v.x *= SCALE; v.y *= SCALE; v.z *= SCALE; v.w *= SCALE;
        *reinterpret_cast<float4*>(&q_lds[qr * QP + c * 4]) = v;
    }

    float acc0 = 0.f, acc1 = 0.f, acc2 = 0.f, acc3 = 0.f;  // out[q0+j][dv=lane]
    float den0 = 0.f, den1 = 0.f, den2 = 0.f, den3 = 0.f;

    for (int t = 0; t < ntiles; ++t) {
        const int kt = key_base + t * TILE;
        __syncthreads();   // prev tile fully consumed (also covers Q staging)

        // ---- stage K (pitch 68) + V (pitch 64), coalesced 1KB/wave-instr ----
        #pragma unroll
        for (int i = 0; i < 4; ++i) {
            const int idx = i * THREADS + tid;      // 0..1023
            const int r = idx >> 4, c = idx & 15;   // row, 16B chunk
            const size_t grow = ((size_t)b * KVn + kt + r) * Dn + c * 4;
            float4 kv = *reinterpret_cast<const float4*>(key + grow);
            *reinterpret_cast<float4*>(&k_lds[r * KP + c * 4]) = kv;
            float4 vv = *reinterpret_cast<const float4*>(value + grow);
            *reinterpret_cast<float4*>(&v_lds[r * VP + c * 4]) = vv;
        }
        __syncthreads();

        // ---- QK^T: lane = key row, wave computes its 4 q's ----
        float s0 = 0.f, s1 = 0.f, s2 = 0.f, s3 = 0.f;
        #pragma unroll
        for (int d0 = 0; d0 < Dn; d0 += 4) {
            const float4 kv = *reinterpret_cast<const float4*>(&k_lds[lane * KP + d0]);
            const float4 qa = *reinterpret_cast<const float4*>(&q_lds[(q0 + 0) * QP + d0]);
            const float4 qb = *reinterpret_cast<const float4*>(&q_lds[(q0 + 1) * QP + d0]);
            const float4 qc = *reinterpret_cast<const float4*>(&q_lds[(q0 + 2) * QP + d0]);
            const float4 qd = *reinterpret_cast<const float4*>(&q_lds[(q0 + 3) * QP + d0]);
            s0 = dot4(kv, qa, s0);
            s1 = dot4(kv, qb, s1);
            s2 = dot4(kv, qc, s2);
            s3 = dot4(kv, qd, s3);
        }
        *reinterpret_cast<float4*>(&s_lds[lane * SP + w * 4]) =
            make_float4(s0, s1, s2, s3);
        __syncthreads();

        // ---- softmax over q (16 values) per key; redundant across waves ----
        const float4 e0 = *reinterpret_cast<const float4*>(&s_lds[lane * SP + 0]);
        const float4 e1 = *reinterpret_cast<const float4*>(&s_lds[lane * SP + 4]);
        const float4 e2 = *reinterpret_cast<const float4*>(&s_lds[lane * SP + 8]);
        const float4 e3 = *reinterpret_cast<const float4*>(&s_lds[lane * SP + 12]);
        float m = fmaxf(fmaxf(fmaxf(e0.x, e0.y), fmaxf(e0.z, e0.w)),
                        fmaxf(fmaxf(e1.x, e1.y), fmaxf(e1.z, e1.w)));
        m = fmaxf(m, fmaxf(fmaxf(fmaxf(e2.x, e2.y), fmaxf(e2.z, e2.w)),
                           fmaxf(fmaxf(e3.x, e3.y), fmaxf(e3.z, e3.w))));
        float4 x0, x1, x2, x3;
        x0.x = exp2f(e0.x - m); x0.y = exp2f(e0.y - m); x0.z = exp2f(e0.z - m); x0.w = exp2f(e0.w - m);
        x1.x = exp2f(e1.x - m); x1.y = exp2f(e1.y - m); x1.z = exp2f(e1.z - m); x1.w = exp2f(e1.w - m);
        x2.x = exp2f(e2.x - m); x2.y = exp2f(e2.y - m); x2.z = exp2f(e2.z - m); x2.w = exp2f(e2.w - m);
        x3.x = exp2f(e3.x - m); x3.y = exp2f(e3.y - m); x3.z = exp2f(e3.z - m); x3.w = exp2f(e3.w - m);
        const float sumq = (x0.x + x0.y + x0.z + x0.w) + (x1.x + x1.y + x1.z + x1.w)
                         + (x2.x + x2.y + x2.z + x2.w) + (x3.x + x3.y + x3.z + x3.w);
        const float inv = 1.0f / sumq;
        const float4 mine = (w == 0) ? x0 : (w == 1) ? x1 : (w == 2) ? x2 : x3;
        const float a0 = mine.x * inv, a1 = mine.y * inv,
                    a2 = mine.z * inv, a3 = mine.w * inv;
        a_lds[(q0 + 0) * AP + lane] = a0;
        a_lds[(q0 + 1) * AP + lane] = a1;
        a_lds[(q0 + 2) * AP + lane] = a2;
        a_lds[(q0 + 3) * AP + lane] = a3;
        den0 += a0; den1 += a1; den2 += a2; den3 += a3;
        __syncthreads();

        // ---- PV: wave owns (its 4 q's) x (dv = lane); loop keys ----
        #pragma unroll
        for (int k0 = 0; k0 < TILE; k0 += 4) {
            const float4 a0v = *reinterpret_cast<const float4*>(&a_lds[(q0 + 0) * AP + k0]);
            const float4 a1v = *reinterpret_cast<const float4*>(&a_lds[(q0 + 1) * AP + k0]);
            const float4 a2v = *reinterpret_cast<const float4*>(&a_lds[(q0 + 2) * AP + k0]);
            const float4 a3v = *reinterpret_cast<const float4*>(&a_lds[(q0 + 3) * AP + k0]);
            {
                const float vv = v_lds[(k0 + 0) * VP + lane];
                acc0 = fmaf(a0v.x, vv, acc0); acc1 = fmaf(a1v.x, vv, acc1);
                acc2 = fmaf(a2v.x, vv, acc2); acc3 = fmaf(a3v.x, vv, acc3);
            }
            {
                const float vv = v_lds[(k0 + 1) * VP + lane];
                acc0 = fmaf(a0v.y, vv, acc0); acc1 = fmaf(a1v.y, vv, acc1);
                acc2 = fmaf(a2v.y, vv, acc2); acc3 = fmaf(a3v.y, vv, acc3);
            }
            {
                const float vv = v_lds[(k0 + 2) * VP + lane];
                acc0 = fmaf(a0v.z, vv, acc0); acc1 = fmaf(a1v.z, vv, acc1);
                acc2 = fmaf(a2v.z, vv, acc2); acc3 = fmaf(a3v.z, vv, acc3);
            }
            {
                const float vv = v_lds[(k0 + 3) * VP + lane];
                acc0 = fmaf(a0v.w, vv, acc0); acc1 = fmaf(a1v.w, vv, acc1);
                acc2 = fmaf(a2v.w, vv, acc2); acc3 = fmaf(a3v.w, vv, acc3);
            }
        }
    }

    // ---- write partial PV outputs (coalesced, 256B rows) ----
    const size_t obase = (((size_t)b * splits + spl) * QN) * DVn;
    pout[obase + (q0 + 0) * DVn + lane] = acc0;
    pout[obase + (q0 + 1) * DVn + lane] = acc1;
    pout[obase + (q0 + 2) * DVn + lane] = acc2;
    pout[obase + (q0 + 3) * DVn + lane] = acc3;

    // ---- wave-reduce denom partials, write 4 scalars ----
    #pragma unroll
    for (int off = 32; off > 0; off >>= 1) {
        den0 += __shfl_down(den0, off, 64);
        den1 += __shfl_down(den1, off, 64);
        den2 += __shfl_down(den2, off, 64);
        den3 += __shfl_down(den3, off, 64);
    }
    if (lane == 0) {
        const size_t dbase = ((size_t)b * splits + spl) * QN;
        pden[dbase + q0 + 0] = den0;
        pden[dbase + q0 + 1] = den1;
        pden[dbase + q0 + 2] = den2;
        pden[dbase + q0 + 3] = den3;
    }
}

__global__ __launch_bounds__(256)
void inv_attn_reduce(const float* __restrict__ pout,
                     const float* __restrict__ pden,
                     float* __restrict__ out,
                     int splits)
{
    const int gid = blockIdx.x * blockDim.x + threadIdx.x;   // 0..65535
    const int dv = gid & 63;
    const int q  = (gid >> 6) & (QN - 1);
    const int b  = gid >> 10;
    float sum = 0.f, den = 0.f;
    #pragma unroll 8
    for (int sp = 0; sp < splits; ++sp) {
        sum += pout[(((size_t)b * splits + sp) * QN + q) * DVn + dv];
        den += pden[((size_t)b * splits + sp) * QN + q];
    }
    out[gid] = sum / (den + 1e-8f);
}

}  // namespace

extern "C" void kernel_launch(void* const* d_in, const int* in_sizes, int n_in,
                              void* d_out, int out_size, void* d_ws, size_t ws_size,
                              hipStream_t stream) {
    const float* query = (const float*)d_in[0];
    const float* key   = (const float*)d_in[1];
    const float* value = (const float*)d_in[2];
    float* out = (float*)d_out;

    // Pick the largest split count whose partials fit in d_ws (deterministic:
    // ws_size is fixed by the harness).
    int splits = MAX_SPLITS;
    auto need = [](int s) {
        return (size_t)Bn * s * QN * DVn * sizeof(float)
             + (size_t)Bn * s * QN * sizeof(float);
    };
    while (splits > 1 && need(splits) > ws_size) splits >>= 1;

    float* pout = (float*)d_ws;
    float* pden = pout + (size_t)Bn * splits * QN * DVn;

    const int ntiles = KVn / (splits * TILE);   // tiles per block

    dim3 grid1(splits, Bn);
    inv_attn_part<<<grid1, THREADS, 0, stream>>>(query, key, value, pout, pden, ntiles);

    const int total = Bn * QN * DVn;            // 65536
    inv_attn_reduce<<<total / 256, 256, 0, stream>>>(pout, pden, out, splits);
}